// Round 6
// baseline (442.182 us; speedup 1.0000x reference)
//
#include <hip/hip_runtime.h>
#include <hip/hip_bf16.h>

typedef float  f32x4  __attribute__((ext_vector_type(4)));
typedef __bf16 bf16x8 __attribute__((ext_vector_type(8)));
typedef __bf16 bf16x4 __attribute__((ext_vector_type(4)));

#define D_  512
#define H_  8
#define HD_ 64
#define B_  256
#define N_  144
#define M_  (B_*N_)   // 36864

using gptr_t = const __attribute__((address_space(1))) char*;
using lptr_t = __attribute__((address_space(3))) char*;
#define GLDS16(gp, lp) __builtin_amdgcn_global_load_lds((gptr_t)(gp), (lptr_t)(lp), 16, 0, 0)

// ---------------- weight prep: f32 -> bf16 ----------------
__global__ void prep_weights_kernel(const float* __restrict__ kvw,
                                    const float* __restrict__ qw,
                                    const float* __restrict__ pw,
                                    __bf16* __restrict__ kvb,
                                    __bf16* __restrict__ qb,
                                    __bf16* __restrict__ pb) {
    int idx = blockIdx.x * 256 + threadIdx.x;
    const float* s; __bf16* d; int off;
    if (idx < 131072)      { s = kvw; d = kvb; off = idx; }
    else if (idx < 196608) { s = qw;  d = qb;  off = idx - 131072; }
    else                   { s = pw;  d = pb;  off = idx - 196608; }
    f32x4 v = *(const f32x4*)(s + (size_t)off * 4);
    bf16x4 o;
    o[0] = (__bf16)v.x; o[1] = (__bf16)v.y; o[2] = (__bf16)v.z; o[3] = (__bf16)v.w;
    *(bf16x4*)(d + (size_t)off * 4) = o;
}

// ------------- activation prep: xb = bf16(x), ab = bf16(x + tf*topo) -------------
__global__ void prep_act_kernel(const float* __restrict__ x,
                                const float* __restrict__ topo,
                                const int* __restrict__ is_end,
                                __bf16* __restrict__ xb,
                                __bf16* __restrict__ ab) {
    const float tf = (is_end[0] != 0) ? 1.f : 0.f;
    const size_t total = (size_t)M_ * D_ / 8;
    for (size_t i = (size_t)blockIdx.x * 256 + threadIdx.x; i < total;
         i += (size_t)gridDim.x * 256) {
        f32x4 a0 = *(const f32x4*)(x + i * 8);
        f32x4 a1 = *(const f32x4*)(x + i * 8 + 4);
        f32x4 t0 = *(const f32x4*)(topo + i * 8);
        f32x4 t1 = *(const f32x4*)(topo + i * 8 + 4);
        bf16x8 xo, ao;
#pragma unroll
        for (int j = 0; j < 4; ++j) {
            xo[j]     = (__bf16)a0[j];
            xo[j + 4] = (__bf16)a1[j];
            ao[j]     = (__bf16)(a0[j] + tf * t0[j]);
            ao[j + 4] = (__bf16)(a1[j] + tf * t1[j]);
        }
        *(bf16x8*)(xb + i * 8) = xo;
        *(bf16x8*)(ab + i * 8) = ao;
    }
}

// ---------------- bf16 GEMM, 128x128 tile, BK=64, prefetch double-buffer ----------------
// One __syncthreads per K-step; stage(t+1) issued before compute(t) so the 16
// global_load_lds have the whole MFMA phase to land (T3-minimum, m230-V0 pattern).
template<int MODE>
__device__ __forceinline__ void mm_body(const __bf16* __restrict__ ab,
                                        const __bf16* __restrict__ xb,
                                        const __bf16* __restrict__ kvb,
                                        const __bf16* __restrict__ qb,
                                        __bf16* __restrict__ kout,
                                        __bf16* __restrict__ vTout,
                                        __bf16* __restrict__ qout,
                                        const float* __restrict__ bias,
                                        float* __restrict__ pout) {
    __shared__ __bf16 As[2][128 * 64];   // 2 x 16 KiB
    __shared__ __bf16 Bs[2][128 * 64];

    const int tid  = threadIdx.x;
    const int lane = tid & 63;
    const int wid  = tid >> 6;
    const int lrow = lane & 15, lhi = lane >> 4;
    const int wr   = wid >> 1,  wc  = wid & 1;

    // bijective XCD swizzle: contiguous wg chunk per XCD; consecutive wg share mb
    const int NB  = (MODE == 0) ? 12 : 4;
    const int per = (MODE == 0) ? 432 : 144;   // nwg/8
    const int bid = blockIdx.x;
    const int wg  = (bid & 7) * per + (bid >> 3);
    const int mb  = wg / NB;
    const int nb  = wg - mb * NB;
    const int m0  = mb * 128;

    const __bf16* Ap;
    const __bf16* Bp;
    if (MODE == 0) {
        Ap = (nb < 8) ? ab : xb;
        Bp = (nb < 8) ? (kvb + (size_t)nb * 128 * D_) : (qb + (size_t)(nb - 8) * 128 * D_);
    } else {
        Ap = ab;
        Bp = kvb + (size_t)nb * 128 * D_;
    }

    f32x4 acc[4][4];
#pragma unroll
    for (int i = 0; i < 4; ++i)
#pragma unroll
        for (int j = 0; j < 4; ++j) acc[i][j] = (f32x4){0.f, 0.f, 0.f, 0.f};

    const int srow = lane >> 3;
    const int scol = (lane & 7) * 16;

    auto stage = [&](int buf, int kt) {
        const int k0 = kt * 64;
        const char* Agb = (const char*)(Ap + (size_t)m0 * D_ + k0);
        const char* Bgb = (const char*)(Bp + k0);
#pragma unroll
        for (int j = 0; j < 4; ++j) {
            const int chunk = wid * 4 + j;           // 0..15, 1 KiB each
            const int row   = chunk * 8 + srow;
            GLDS16(Agb + (size_t)row * (D_ * 2) + scol, (char*)As[buf] + chunk * 1024);
            GLDS16(Bgb + (size_t)row * (D_ * 2) + scol, (char*)Bs[buf] + chunk * 1024);
        }
    };

    stage(0, 0);
    int cur = 0;
    for (int kt = 0; kt < 8; ++kt) {
        __syncthreads();                 // drains stage(cur); waves done reading cur^1
        if (kt < 7) stage(cur ^ 1, kt + 1);   // prefetch overlaps compute below
#pragma unroll
        for (int kk = 0; kk < 2; ++kk) {
            bf16x8 af[4], bfr[4];
#pragma unroll
            for (int mi = 0; mi < 4; ++mi)
                af[mi] = *(const bf16x8*)((const char*)As[cur] +
                          (wr * 64 + mi * 16 + lrow) * 128 + kk * 64 + lhi * 16);
#pragma unroll
            for (int ni = 0; ni < 4; ++ni)
                bfr[ni] = *(const bf16x8*)((const char*)Bs[cur] +
                          (wc * 64 + ni * 16 + lrow) * 128 + kk * 64 + lhi * 16);
#pragma unroll
            for (int mi = 0; mi < 4; ++mi)
#pragma unroll
                for (int ni = 0; ni < 4; ++ni)
                    acc[mi][ni] = __builtin_amdgcn_mfma_f32_16x16x32_bf16(
                        af[mi], bfr[ni], acc[mi][ni], 0, 0, 0);
        }
        cur ^= 1;
    }

    // ---- epilogue: C row = (lane>>4)*4+reg, col = lane&15 (m89-verified) ----
    float bv4[4];
    if (MODE == 1) {
#pragma unroll
        for (int ni = 0; ni < 4; ++ni) bv4[ni] = bias[nb * 128 + wc * 64 + ni * 16 + lrow];
    }
#pragma unroll
    for (int mi = 0; mi < 4; ++mi) {
#pragma unroll
        for (int reg = 0; reg < 4; ++reg) {
            int m  = m0 + wr * 64 + mi * 16 + lhi * 4 + reg;
            int bb = m / N_;
            int nn = m - bb * N_;
#pragma unroll
            for (int ni = 0; ni < 4; ++ni) {
                const int ol = wc * 64 + ni * 16 + lrow;
                float val = acc[mi][ni][reg];
                if (MODE == 0) {
                    const int o = nb * 128 + ol;
                    if (nb < 8) {
                        int hh = (o >> 6) & 7;
                        int dd = o & 63;
                        if (o < 512)
                            kout[(((size_t)bb * H_ + hh) * N_ + nn) * HD_ + dd] = (__bf16)val;
                        else
                            vTout[(((size_t)bb * H_ + hh) * HD_ + dd) * N_ + nn] = (__bf16)val;
                    } else {
                        int o2 = o - 1024;
                        int hh = o2 >> 6, dd = o2 & 63;
                        qout[(((size_t)bb * H_ + hh) * N_ + nn) * HD_ + dd] = (__bf16)val;
                    }
                } else {
                    pout[(size_t)m * D_ + nb * 128 + ol] = val + bv4[ni];
                }
            }
        }
    }
}

__global__ __launch_bounds__(256, 2) void mm0_kernel(
        const __bf16* __restrict__ ab, const __bf16* __restrict__ xb,
        const __bf16* __restrict__ kvb, const __bf16* __restrict__ qb,
        __bf16* __restrict__ kout, __bf16* __restrict__ vTout,
        __bf16* __restrict__ qout) {
    mm_body<0>(ab, xb, kvb, qb, kout, vTout, qout, nullptr, nullptr);
}

__global__ __launch_bounds__(256, 2) void mm1_kernel(
        const __bf16* __restrict__ ab, const __bf16* __restrict__ pwb,
        const float* __restrict__ bias, float* __restrict__ pout) {
    mm_body<1>(ab, nullptr, pwb, nullptr, nullptr, nullptr, nullptr, bias, pout);
}

// ---------------- attention: ONE WAVE per (b,h,q-tile) ----------------
// No K/V LDS staging (K/V are 18 KB/head, L2-resident, reused by 9 tile-blocks
// that the XCD-chunk swizzle colocates). Only per-wave Ps[16][168] for the
// P-transpose round trip (stride 168 = 2-way banks, was 8-way at 160).
// Zero barriers; 18432 independent 64-thread blocks for latency hiding.
__launch_bounds__(64)
__global__ void attn_kernel(const __bf16* __restrict__ qbuf,
                            const __bf16* __restrict__ kbuf,
                            const __bf16* __restrict__ vTbuf,
                            __bf16* __restrict__ aout) {
    __shared__ __bf16 Ps[16][168];   // 5376 B

    const int lane = threadIdx.x & 63;
    const int lrow = lane & 15, lhi = lane >> 4;
    const int bid  = blockIdx.x;
    const int w    = (bid & 7) * 2304 + (bid >> 3);   // XCD chunk swizzle (8x2304)
    const int bh   = w / 9;
    const int t    = w - bh * 9;
    const int bb   = bh >> 3, hh = bh & 7;

    const __bf16* kg = kbuf  + (size_t)bh * (N_ * HD_);
    const __bf16* vg = vTbuf + (size_t)bh * (N_ * HD_);
    const __bf16* qg = qbuf  + (size_t)bh * (N_ * HD_);

    // zero P pad cols 144..159 (read by kc=4 against garbage V — product must be 0)
    bf16x8 z8;
#pragma unroll
    for (int i = 0; i < 8; ++i) z8[i] = (__bf16)0.f;
    if (lane < 32)
        *(bf16x8*)&Ps[lane >> 1][144 + (lane & 1) * 8] = z8;

    const float sc = 0.125f * 1.44269504089f;     // scale * log2(e)

    // Q fragment for this tile
    bf16x8 aq[2];
#pragma unroll
    for (int kk = 0; kk < 2; ++kk)
        aq[kk] = *(const bf16x8*)(qg + (t * 16 + lrow) * 64 + kk * 32 + lhi * 8);

    // S = Q K^T : s[j][reg] = S[q = t*16+lhi*4+reg][k = j*16+lrow]
    f32x4 s[9];
#pragma unroll
    for (int j = 0; j < 9; ++j) s[j] = (f32x4){0.f, 0.f, 0.f, 0.f};
#pragma unroll
    for (int j = 0; j < 9; ++j)
#pragma unroll
        for (int kk = 0; kk < 2; ++kk)
            s[j] = __builtin_amdgcn_mfma_f32_16x16x32_bf16(
                aq[kk],
                *(const bf16x8*)(kg + (j * 16 + lrow) * 64 + kk * 32 + lhi * 8),
                s[j], 0, 0, 0);

    // wave-parallel softmax over k (9 frags in-register x 16 lanes)
    float inv[4];
#pragma unroll
    for (int reg = 0; reg < 4; ++reg) {
        float mx = s[0][reg];
#pragma unroll
        for (int j = 1; j < 9; ++j) mx = fmaxf(mx, s[j][reg]);
#pragma unroll
        for (int off = 1; off < 16; off <<= 1) mx = fmaxf(mx, __shfl_xor(mx, off, 16));
        float sum = 0.f;
#pragma unroll
        for (int j = 0; j < 9; ++j) {
            float p = exp2f((s[j][reg] - mx) * sc);
            s[j][reg] = p;
            sum += p;
        }
#pragma unroll
        for (int off = 1; off < 16; off <<= 1) sum += __shfl_xor(sum, off, 16);
        inv[reg] = 1.f / sum;
    }

    // P transpose through LDS: write P[q][k]
#pragma unroll
    for (int j = 0; j < 9; ++j)
#pragma unroll
        for (int reg = 0; reg < 4; ++reg)
            Ps[lhi * 4 + reg][j * 16 + lrow] = (__bf16)(s[j][reg] * inv[reg]);

    // PV: out[16,64] = P[16,160] @ V^T[64,160]^T  (P cols 144..159 are zero)
#pragma unroll
    for (int dc = 0; dc < 4; ++dc) {
        f32x4 o4 = (f32x4){0.f, 0.f, 0.f, 0.f};
#pragma unroll
        for (int kc = 0; kc < 5; ++kc)
            o4 = __builtin_amdgcn_mfma_f32_16x16x32_bf16(
                *(const bf16x8*)&Ps[lrow][kc * 32 + lhi * 8],
                *(const bf16x8*)(vg + (dc * 16 + lrow) * 144 + kc * 32 + lhi * 8),
                o4, 0, 0, 0);
#pragma unroll
        for (int reg = 0; reg < 4; ++reg) {
            int nn = t * 16 + lhi * 4 + reg;
            int dd = dc * 16 + lrow;
            aout[((size_t)bb * N_ + nn) * D_ + hh * HD_ + dd] = (__bf16)o4[reg];
        }
    }
}

extern "C" void kernel_launch(void* const* d_in, const int* in_sizes, int n_in,
                              void* d_out, int out_size, void* d_ws, size_t ws_size,
                              hipStream_t stream) {
    const float* x      = (const float*)d_in[0];
    const float* topo   = (const float*)d_in[1];
    const float* kvw    = (const float*)d_in[2];
    const float* qw     = (const float*)d_in[3];
    const float* pw     = (const float*)d_in[4];
    const float* pb     = (const float*)d_in[5];
    const int*   is_end = (const int*)d_in[6];
    float* out = (float*)d_out;

    char* ws = (char*)d_ws;
    __bf16* kvb = (__bf16*)(ws);                       // 1 MiB
    __bf16* qb  = (__bf16*)(ws + (1u << 20));          // 512 KiB
    __bf16* pwb = (__bf16*)(ws + (1u << 20) + 524288); // 512 KiB
    size_t off = (1u << 20) + 2 * 524288;
    const size_t BUF = (size_t)M_ * D_ * 2;            // 37748736 B each
    __bf16* xb    = (__bf16*)(ws + off); off += BUF;   // bf16(x); reused as abuf later
    __bf16* ab    = (__bf16*)(ws + off); off += BUF;   // bf16(x + tf*topo)
    __bf16* kbuf  = (__bf16*)(ws + off); off += BUF;
    __bf16* vTbuf = (__bf16*)(ws + off); off += BUF;
    __bf16* qbuf  = (__bf16*)(ws + off); off += BUF;   // must stay right after vTbuf
    __bf16* abuf  = xb;   // xb dead after mm0; alias to stay within ws

    prep_weights_kernel<<<1024, 256, 0, stream>>>(kvw, qw, pw, kvb, qb, pwb);
    prep_act_kernel<<<2048, 256, 0, stream>>>(x, topo, is_end, xb, ab);
    mm0_kernel<<<3456, 256, 0, stream>>>(ab, xb, kvb, qb, kbuf, vTbuf, qbuf);
    attn_kernel<<<18432, 64, 0, stream>>>(qbuf, kbuf, vTbuf, abuf);
    mm1_kernel<<<1152, 256, 0, stream>>>(abuf, pwb, pb, out);
}

// Round 7
// 371.221 us; speedup vs baseline: 1.1912x; 1.1912x over previous
//
#include <hip/hip_runtime.h>
#include <hip/hip_bf16.h>

typedef float  f32x4  __attribute__((ext_vector_type(4)));
typedef __bf16 bf16x8 __attribute__((ext_vector_type(8)));
typedef __bf16 bf16x4 __attribute__((ext_vector_type(4)));

#define D_  512
#define H_  8
#define HD_ 64
#define B_  256
#define N_  144
#define M_  (B_*N_)   // 36864

using gptr_t = const __attribute__((address_space(1))) char*;
using lptr_t = __attribute__((address_space(3))) char*;
#define GLDS16(gp, lp) __builtin_amdgcn_global_load_lds((gptr_t)(gp), (lptr_t)(lp), 16, 0, 0)

// ---------------- weight prep: f32 -> bf16 ----------------
__global__ void prep_weights_kernel(const float* __restrict__ kvw,
                                    const float* __restrict__ qw,
                                    const float* __restrict__ pw,
                                    __bf16* __restrict__ kvb,
                                    __bf16* __restrict__ qb,
                                    __bf16* __restrict__ pb) {
    int idx = blockIdx.x * 256 + threadIdx.x;
    const float* s; __bf16* d; int off;
    if (idx < 131072)      { s = kvw; d = kvb; off = idx; }
    else if (idx < 196608) { s = qw;  d = qb;  off = idx - 131072; }
    else                   { s = pw;  d = pb;  off = idx - 196608; }
    f32x4 v = *(const f32x4*)(s + (size_t)off * 4);
    bf16x4 o;
    o[0] = (__bf16)v.x; o[1] = (__bf16)v.y; o[2] = (__bf16)v.z; o[3] = (__bf16)v.w;
    *(bf16x4*)(d + (size_t)off * 4) = o;
}

// ------------- activation prep: xb = bf16(x), ab = bf16(x + tf*topo) -------------
__global__ void prep_act_kernel(const float* __restrict__ x,
                                const float* __restrict__ topo,
                                const int* __restrict__ is_end,
                                __bf16* __restrict__ xb,
                                __bf16* __restrict__ ab) {
    const float tf = (is_end[0] != 0) ? 1.f : 0.f;
    const size_t total = (size_t)M_ * D_ / 8;
    for (size_t i = (size_t)blockIdx.x * 256 + threadIdx.x; i < total;
         i += (size_t)gridDim.x * 256) {
        f32x4 a0 = *(const f32x4*)(x + i * 8);
        f32x4 a1 = *(const f32x4*)(x + i * 8 + 4);
        f32x4 t0 = *(const f32x4*)(topo + i * 8);
        f32x4 t1 = *(const f32x4*)(topo + i * 8 + 4);
        bf16x8 xo, ao;
#pragma unroll
        for (int j = 0; j < 4; ++j) {
            xo[j]     = (__bf16)a0[j];
            xo[j + 4] = (__bf16)a1[j];
            ao[j]     = (__bf16)(a0[j] + tf * t0[j]);
            ao[j + 4] = (__bf16)(a1[j] + tf * t1[j]);
        }
        *(bf16x8*)(xb + i * 8) = xo;
        *(bf16x8*)(ab + i * 8) = ao;
    }
}

// ---------------- bf16 GEMM, m97 structure (R5): 128x128, BK=64, single buffer ----------
// MODE 0 adds an LDS-bounce epilogue: acc -> Ct[128][130] -> fully-coalesced stores
// (V^T was 2B/lane stride-288B scatter = 64 sectors/instr; now 128B/instr).
template<int MODE>
__device__ __forceinline__ void mm_body(const __bf16* __restrict__ ab,
                                        const __bf16* __restrict__ xb,
                                        const __bf16* __restrict__ kvb,
                                        const __bf16* __restrict__ qb,
                                        __bf16* __restrict__ kout,
                                        __bf16* __restrict__ vTout,
                                        __bf16* __restrict__ qout,
                                        const float* __restrict__ bias,
                                        float* __restrict__ pout) {
    // As 16K | Bs 16K during K-loop; MODE 0 epilogue overlays Ct[128][130] (33280 B)
    __shared__ __align__(16) char smem[(MODE == 0) ? 33280 : 32768];
    __bf16* As = (__bf16*)smem;
    __bf16* Bs = (__bf16*)(smem + 16384);

    const int tid  = threadIdx.x;
    const int lane = tid & 63;
    const int wid  = tid >> 6;
    const int lrow = lane & 15, lhi = lane >> 4;
    const int wr   = wid >> 1,  wc  = wid & 1;

    // bijective XCD swizzle: contiguous wg chunk per XCD; consecutive wg share mb
    const int NB  = (MODE == 0) ? 12 : 4;
    const int per = (MODE == 0) ? 432 : 144;   // nwg/8
    const int bid = blockIdx.x;
    const int wg  = (bid & 7) * per + (bid >> 3);
    const int mb  = wg / NB;
    const int nb  = wg - mb * NB;
    const int m0  = mb * 128;

    const __bf16* Ap;
    const __bf16* Bp;
    if (MODE == 0) {
        Ap = (nb < 8) ? ab : xb;
        Bp = (nb < 8) ? (kvb + (size_t)nb * 128 * D_) : (qb + (size_t)(nb - 8) * 128 * D_);
    } else {
        Ap = ab;
        Bp = kvb + (size_t)nb * 128 * D_;
    }

    f32x4 acc[4][4];
#pragma unroll
    for (int i = 0; i < 4; ++i)
#pragma unroll
        for (int j = 0; j < 4; ++j) acc[i][j] = (f32x4){0.f, 0.f, 0.f, 0.f};

    const int srow = lane >> 3;
    const int scol = (lane & 7) * 16;

    for (int kt = 0; kt < 8; ++kt) {
        const int k0 = kt * 64;
        const char* Agb = (const char*)(Ap + (size_t)m0 * D_ + k0);
        const char* Bgb = (const char*)(Bp + k0);
#pragma unroll
        for (int j = 0; j < 4; ++j) {
            const int chunk = wid * 4 + j;           // 0..15, 1 KiB each
            const int row   = chunk * 8 + srow;
            GLDS16(Agb + (size_t)row * (D_ * 2) + scol, (char*)As + chunk * 1024);
            GLDS16(Bgb + (size_t)row * (D_ * 2) + scol, (char*)Bs + chunk * 1024);
        }
        __syncthreads();
#pragma unroll
        for (int kk = 0; kk < 2; ++kk) {
            bf16x8 af[4], bfr[4];
#pragma unroll
            for (int mi = 0; mi < 4; ++mi)
                af[mi] = *(const bf16x8*)((const char*)As +
                          (wr * 64 + mi * 16 + lrow) * 128 + kk * 64 + lhi * 16);
#pragma unroll
            for (int ni = 0; ni < 4; ++ni)
                bfr[ni] = *(const bf16x8*)((const char*)Bs +
                          (wc * 64 + ni * 16 + lrow) * 128 + kk * 64 + lhi * 16);
#pragma unroll
            for (int mi = 0; mi < 4; ++mi)
#pragma unroll
                for (int ni = 0; ni < 4; ++ni)
                    acc[mi][ni] = __builtin_amdgcn_mfma_f32_16x16x32_bf16(
                        af[mi], bfr[ni], acc[mi][ni], 0, 0, 0);
        }
        __syncthreads();
    }

    if (MODE == 0) {
        // ---- epilogue via LDS transpose: Ct row stride 130 (65 dwords, odd -> no bank alias)
        __bf16 (*Ct)[130] = (__bf16 (*)[130])smem;
#pragma unroll
        for (int mi = 0; mi < 4; ++mi)
#pragma unroll
            for (int reg = 0; reg < 4; ++reg) {
                const int r = wr * 64 + mi * 16 + lhi * 4 + reg;
#pragma unroll
                for (int ni = 0; ni < 4; ++ni)
                    Ct[r][wc * 64 + ni * 16 + lrow] = (__bf16)acc[mi][ni][reg];
            }
        __syncthreads();

        if (nb < 8) {
            if (nb < 4) {
                // K blocks: out [bb,hh,nn,dd] — bf16x8, consecutive lanes contiguous 128B
#pragma unroll
                for (int it = 0; it < 8; ++it) {
                    int task = it * 256 + tid;            // [m(7b) | half | j(3b)]
                    int m = task >> 4, half = (task >> 3) & 1, j = task & 7;
                    int mg = m0 + m, bb2 = mg / N_, nn = mg - bb2 * N_;
                    bf16x8 v = *(const bf16x8*)&Ct[m][half * 64 + j * 8];
                    *(bf16x8*)(kout + (((size_t)bb2 * H_ + nb * 2 + half) * N_ + nn) * HD_ + j * 8) = v;
                }
            } else {
                // V blocks: out [bb,hh,dd,nn] — lane = consecutive nn (coalesced 128B)
                for (int it = 0; it < 64; ++it) {
                    int task = wid * 64 + it;             // ol(7b) | seg
                    int ol = task >> 1, seg = task & 1;
                    int m = seg * 64 + lane;
                    int mg = m0 + m, bb2 = mg / N_, nn = mg - bb2 * N_;
                    int hh = (nb - 4) * 2 + (ol >> 6), dd = ol & 63;
                    vTout[(((size_t)bb2 * H_ + hh) * HD_ + dd) * N_ + nn] = Ct[m][ol];
                }
            }
        } else {
            // Q blocks: same shape as K
#pragma unroll
            for (int it = 0; it < 8; ++it) {
                int task = it * 256 + tid;
                int m = task >> 4, half = (task >> 3) & 1, j = task & 7;
                int mg = m0 + m, bb2 = mg / N_, nn = mg - bb2 * N_;
                bf16x8 v = *(const bf16x8*)&Ct[m][half * 64 + j * 8];
                *(bf16x8*)(qout + (((size_t)bb2 * H_ + (nb - 8) * 2 + half) * N_ + nn) * HD_ + j * 8) = v;
            }
        }
    } else {
        // MODE 1: direct f32 + bias (already coalesced: 16 lanes x 4B contiguous)
        float bv4[4];
#pragma unroll
        for (int ni = 0; ni < 4; ++ni) bv4[ni] = bias[nb * 128 + wc * 64 + ni * 16 + lrow];
#pragma unroll
        for (int mi = 0; mi < 4; ++mi)
#pragma unroll
            for (int reg = 0; reg < 4; ++reg) {
                int m = m0 + wr * 64 + mi * 16 + lhi * 4 + reg;
#pragma unroll
                for (int ni = 0; ni < 4; ++ni)
                    pout[(size_t)m * D_ + nb * 128 + wc * 64 + ni * 16 + lrow] =
                        acc[mi][ni][reg] + bv4[ni];
            }
    }
}

__global__ __launch_bounds__(256, 3) void mm0_kernel(
        const __bf16* __restrict__ ab, const __bf16* __restrict__ xb,
        const __bf16* __restrict__ kvb, const __bf16* __restrict__ qb,
        __bf16* __restrict__ kout, __bf16* __restrict__ vTout,
        __bf16* __restrict__ qout) {
    mm_body<0>(ab, xb, kvb, qb, kout, vTout, qout, nullptr, nullptr);
}

__global__ __launch_bounds__(256, 3) void mm1_kernel(
        const __bf16* __restrict__ ab, const __bf16* __restrict__ pwb,
        const float* __restrict__ bias, float* __restrict__ pout) {
    mm_body<1>(ab, nullptr, pwb, nullptr, nullptr, nullptr, nullptr, bias, pout);
}

// ---------------- attention: one block per (b,h) (R5 version, best measured) ----------
__launch_bounds__(256, 2)
__global__ void attn_kernel(const __bf16* __restrict__ qbuf,
                            const __bf16* __restrict__ kbuf,
                            const __bf16* __restrict__ vTbuf,
                            __bf16* __restrict__ aout) {
    __shared__ __bf16 Ks[144][72];     // 20736 B
    __shared__ __bf16 Vs[64][168];     // 21504 B (cols 144..167 zero)
    __shared__ __bf16 Ps[4][16][160];  // 20480 B per-wave P tiles

    const int tid  = threadIdx.x;
    const int lane = tid & 63, wid = tid >> 6;
    const int lrow = lane & 15, lhi = lane >> 4;
    const int bh = blockIdx.x;
    const int bb = bh >> 3, hh = bh & 7;

    const __bf16* kg = kbuf  + (size_t)bh * (N_ * HD_);
    const __bf16* vg = vTbuf + (size_t)bh * (N_ * HD_);
    const __bf16* qg = qbuf  + (size_t)bh * (N_ * HD_);

    for (int c = tid; c < 1152; c += 256) {       // K: 144x64
        int row = c >> 3, cc = c & 7;
        *(bf16x8*)&Ks[row][cc * 8] = *(const bf16x8*)(kg + row * 64 + cc * 8);
    }
    for (int c = tid; c < 1152; c += 256) {       // vT: 64x144
        int dd = c / 18, cc = c - dd * 18;
        *(bf16x8*)&Vs[dd][cc * 8] = *(const bf16x8*)(vg + dd * 144 + cc * 8);
    }
    bf16x8 z8;
#pragma unroll
    for (int i = 0; i < 8; ++i) z8[i] = (__bf16)0.f;
    if (tid < 192) {                              // zero pad cols of Vs
        int dd = tid / 3, cc = tid - dd * 3;
        *(bf16x8*)&Vs[dd][144 + cc * 8] = z8;
    }
    if (lhi < 2)                                  // zero pad cols of this wave's Ps
        *(bf16x8*)&Ps[wid][lrow][144 + lhi * 8] = z8;
    __syncthreads();

    const float sc = 0.125f * 1.44269504089f;     // scale * log2(e)

    for (int t = wid; t < 9; t += 4) {            // 16-row tiles of Q
        bf16x8 aq[2];
#pragma unroll
        for (int kk = 0; kk < 2; ++kk)
            aq[kk] = *(const bf16x8*)(qg + (t * 16 + lrow) * 64 + kk * 32 + lhi * 8);

        f32x4 s[9];
#pragma unroll
        for (int j = 0; j < 9; ++j) s[j] = (f32x4){0.f, 0.f, 0.f, 0.f};
#pragma unroll
        for (int j = 0; j < 9; ++j)
#pragma unroll
            for (int kk = 0; kk < 2; ++kk)
                s[j] = __builtin_amdgcn_mfma_f32_16x16x32_bf16(
                    aq[kk], *(const bf16x8*)&Ks[j * 16 + lrow][kk * 32 + lhi * 8], s[j], 0, 0, 0);

        float inv[4];
#pragma unroll
        for (int reg = 0; reg < 4; ++reg) {
            float mx = s[0][reg];
#pragma unroll
            for (int j = 1; j < 9; ++j) mx = fmaxf(mx, s[j][reg]);
#pragma unroll
            for (int off = 1; off < 16; off <<= 1) mx = fmaxf(mx, __shfl_xor(mx, off, 16));
            float sum = 0.f;
#pragma unroll
            for (int j = 0; j < 9; ++j) {
                float p = exp2f((s[j][reg] - mx) * sc);
                s[j][reg] = p;
                sum += p;
            }
#pragma unroll
            for (int off = 1; off < 16; off <<= 1) sum += __shfl_xor(sum, off, 16);
            inv[reg] = 1.f / sum;
        }
#pragma unroll
        for (int j = 0; j < 9; ++j)
#pragma unroll
            for (int reg = 0; reg < 4; ++reg)
                Ps[wid][lhi * 4 + reg][j * 16 + lrow] = (__bf16)(s[j][reg] * inv[reg]);

        // PV: out[16,64] = P[16,160] @ V[160,64]  (K padded with zeros)
#pragma unroll
        for (int dc = 0; dc < 4; ++dc) {
            f32x4 o4 = (f32x4){0.f, 0.f, 0.f, 0.f};
#pragma unroll
            for (int kc = 0; kc < 5; ++kc)
                o4 = __builtin_amdgcn_mfma_f32_16x16x32_bf16(
                    *(const bf16x8*)&Ps[wid][lrow][kc * 32 + lhi * 8],
                    *(const bf16x8*)&Vs[dc * 16 + lrow][kc * 32 + lhi * 8], o4, 0, 0, 0);
#pragma unroll
            for (int reg = 0; reg < 4; ++reg) {
                int nn = t * 16 + lhi * 4 + reg;
                int dd = dc * 16 + lrow;
                aout[((size_t)bb * N_ + nn) * D_ + hh * HD_ + dd] = (__bf16)o4[reg];
            }
        }
    }
}

extern "C" void kernel_launch(void* const* d_in, const int* in_sizes, int n_in,
                              void* d_out, int out_size, void* d_ws, size_t ws_size,
                              hipStream_t stream) {
    const float* x      = (const float*)d_in[0];
    const float* topo   = (const float*)d_in[1];
    const float* kvw    = (const float*)d_in[2];
    const float* qw     = (const float*)d_in[3];
    const float* pw     = (const float*)d_in[4];
    const float* pb     = (const float*)d_in[5];
    const int*   is_end = (const int*)d_in[6];
    float* out = (float*)d_out;

    char* ws = (char*)d_ws;
    __bf16* kvb = (__bf16*)(ws);                       // 1 MiB
    __bf16* qb  = (__bf16*)(ws + (1u << 20));          // 512 KiB
    __bf16* pwb = (__bf16*)(ws + (1u << 20) + 524288); // 512 KiB
    size_t off = (1u << 20) + 2 * 524288;
    const size_t BUF = (size_t)M_ * D_ * 2;            // 37748736 B each
    __bf16* xb    = (__bf16*)(ws + off); off += BUF;   // bf16(x); reused as abuf later
    __bf16* ab    = (__bf16*)(ws + off); off += BUF;   // bf16(x + tf*topo)
    __bf16* kbuf  = (__bf16*)(ws + off); off += BUF;
    __bf16* vTbuf = (__bf16*)(ws + off); off += BUF;
    __bf16* qbuf  = (__bf16*)(ws + off); off += BUF;
    __bf16* abuf  = xb;   // xb dead after mm0; alias to stay within ws

    prep_weights_kernel<<<1024, 256, 0, stream>>>(kvw, qw, pw, kvb, qb, pwb);
    prep_act_kernel<<<2048, 256, 0, stream>>>(x, topo, is_end, xb, ab);
    mm0_kernel<<<3456, 256, 0, stream>>>(ab, xb, kvb, qb, kbuf, vTbuf, qbuf);
    attn_kernel<<<2048, 256, 0, stream>>>(qbuf, kbuf, vTbuf, abuf);
    mm1_kernel<<<1152, 256, 0, stream>>>(abuf, pwb, pb, out);
}